// Round 5
// baseline (803.360 us; speedup 1.0000x reference)
//
#include <hip/hip_runtime.h>
#include <stdint.h>

__device__ __forceinline__ float bf2f(uint32_t v) { return __uint_as_float(v << 16); }
__device__ __forceinline__ uint32_t f2bf(float f) {
  uint32_t u = __float_as_uint(f);
  return (u + 0x7fffu + ((u >> 16) & 1u)) >> 16;  // RNE
}

// jax.image.resize bilinear 16->32 closed form (edge renorm == clamp)
__device__ __forceinline__ void interp_coord(int p, int& i0, int& i1, float& f) {
  if (p == 0)       { i0 = 0;  i1 = 0;  f = 0.f; }
  else if (p == 31) { i0 = 15; i1 = 15; f = 0.f; }
  else if (p & 1)   { i0 = (p - 1) >> 1; i1 = i0 + 1; f = 0.25f; }
  else              { i0 = (p >> 1) - 1; i1 = i0 + 1; f = 0.75f; }
}

typedef short bf16x8 __attribute__((ext_vector_type(8)));
typedef float f32x4 __attribute__((ext_vector_type(4)));

// ---------------------------------------------------------------------------
// Kernel A: two-level Haar DWT.  x (32,128,128,128) f32 -> bands bf16
// layout [k][p=h*32+w][b][i].  (R1 version — near coalesced-BW floor)
// ---------------------------------------------------------------------------
__global__ __launch_bounds__(256) void dwt_kernel(const float* __restrict__ x,
                                                  uint16_t* __restrict__ bands) {
  __shared__ uint16_t tile[4 * 32 * 34];  // [k][w][c pad 34], 8.7 KB
  const int bid = blockIdx.x;
  const int cg4 = bid & 3;          // 32-channel group
  const int h   = (bid >> 2) & 31;  // output row
  const int b   = bid >> 7;         // batch
  const int t   = threadIdx.x;
  const int w   = t & 31;           // output col
  const int cl  = t >> 5;           // 0..7
#pragma unroll
  for (int cc = 0; cc < 4; ++cc) {
    const int c = cl + (cc << 3);   // 0..31 local channel
    const float* xc = x + (((size_t)(b << 7) + (cg4 << 5) + c) << 14) + (h << 9) + (w << 2);
    float4 r0 = *(const float4*)(xc);
    float4 r1 = *(const float4*)(xc + 128);
    float4 r2 = *(const float4*)(xc + 256);
    float4 r3 = *(const float4*)(xc + 384);
    float S00 = r0.x + r0.y + r1.x + r1.y;
    float S01 = r0.z + r0.w + r1.z + r1.w;
    float S10 = r2.x + r2.y + r3.x + r3.y;
    float S11 = r2.z + r2.w + r3.z + r3.w;
    tile[(0 * 32 + w) * 34 + c] = (uint16_t)f2bf(0.25f * (S00 + S01 + S10 + S11));  // ll
    tile[(1 * 32 + w) * 34 + c] = (uint16_t)f2bf(0.25f * (S00 - S01 + S10 - S11));  // lh
    tile[(2 * 32 + w) * 34 + c] = (uint16_t)f2bf(0.25f * (S00 + S01 - S10 - S11));  // hl
    tile[(3 * 32 + w) * 34 + c] = (uint16_t)f2bf(0.25f * (S00 - S01 - S10 + S11));  // hh
  }
  __syncthreads();
  const uint32_t* tl = (const uint32_t*)tile;
  uint32_t* bo = (uint32_t*)bands;
#pragma unroll
  for (int j = 0; j < 8; ++j) {
    const int idx = t + (j << 8);   // 0..2047
    const int k   = idx >> 9;
    const int rem = idx & 511;
    const int w2  = rem >> 4;
    const int qq  = rem & 15;       // i-pair within 32-ch group
    const uint32_t v = tl[(k * 32 + w2) * 17 + qq];
    bo[(((size_t)(k << 10) + (h << 5) + w2) << 11) + (b << 6) + (cg4 << 4) + qq] = v;
  }
}

// ---------------------------------------------------------------------------
// Kernel B: repack base weights to bf16 wr[k][yx][o*128+i]  (33.5 MB, now in
// d_ws after the freed ws2 slot — d_out is no longer scratch since the tail
// kernel writes it while reading wr).
// ---------------------------------------------------------------------------
__global__ __launch_bounds__(256) void wrepack_kernel(const float* __restrict__ w1,
                                                      const float* __restrict__ w2,
                                                      const float* __restrict__ w3,
                                                      const float* __restrict__ w4,
                                                      uint16_t* __restrict__ wr) {
  __shared__ uint16_t L[64 * 262];  // [i_local][yx pad 262], 33.5 KB
  const int bid = blockIdx.x;       // 512
  const int k = bid >> 7;
  const int o = bid & 127;
  const float* src = (k == 0) ? w1 : (k == 1) ? w2 : (k == 2) ? w3 : w4;
  const int t = threadIdx.x;
  uint32_t* Lu = (uint32_t*)L;
  for (int ih = 0; ih < 2; ++ih) {    // two halves of i (64 each)
    if (ih) __syncthreads();          // protect LDS reuse
#pragma unroll
    for (int j = 0; j < 16; ++j) {
      const int ridx = t + (j << 8);  // 0..4095
      const int il = ridx >> 6;       // 0..63 local i
      const int x4 = ridx & 63;       // float4 within 256 yx
      float4 v = *(const float4*)(src + (((size_t)((ih * 64 + il) * 128 + o)) << 8) + (x4 << 2));
      Lu[il * 131 + (x4 << 1)]     = f2bf(v.x) | (f2bf(v.y) << 16);
      Lu[il * 131 + (x4 << 1) + 1] = f2bf(v.z) | (f2bf(v.w) << 16);
    }
    __syncthreads();
    // emit: for each yx, i-pairs -> 128B coalesced runs
#pragma unroll
    for (int j = 0; j < 32; ++j) {
      const int oidx = t + (j << 8);  // 0..8191
      const int yx = oidx >> 5;       // 0..255
      const int q  = oidx & 31;       // i-pair within this 64-i half
      const uint32_t lo = L[(q << 1) * 262 + yx];
      const uint32_t hi = L[((q << 1) + 1) * 262 + yx];
      uint32_t* dst = (uint32_t*)wr + (((size_t)(k << 8) + yx) << 13) + (o << 6) + (ih << 5) + q;
      *dst = lo | (hi << 16);
    }
  }
}

// ---------------------------------------------------------------------------
// Kernel T (fused tail = R1 gemm x4k + in-register idwt): one block per p.
// For k=0..3: build Wt[o][i] in LDS (R1-verified coalesced stage + interp),
// 16 MFMA/wave into acc[k].  Then Haar-combine the four accumulators in f32
// registers and write the final 4x4 upsampled output blocks directly —
// eliminates the ws2 intermediate (67 MB round-trip) and the idwt kernel.
// bid swizzle: the 4 blocks covering one w-quad (whose 16B stores share 64B
// lines) are == wq (mod 8) -> same XCD -> lines assemble in one L2.
// ---------------------------------------------------------------------------
__global__ __launch_bounds__(256) void tail_kernel(const uint16_t* __restrict__ bands,
                                                   const uint16_t* __restrict__ wr,
                                                   float* __restrict__ out) {
  __shared__ uint16_t Wt[128 * 136];  // [o][i pad 136], 34.8 KB
  const int bid = blockIdx.x;         // 1024
  const int h  = bid >> 5;
  const int jq = (bid >> 3) & 3;
  const int wq = bid & 7;
  const int w  = (wq << 2) + jq;      // quad-major: w-quad on one XCD
  const int p  = (h << 5) + w;
  const int t  = threadIdx.x;
  // ---- bilinear cell window for this p ----
  int y0, y1, x0, x1; float fy, fx;
  interp_coord(h, y0, y1, fy);
  interp_coord(w, x0, x1, fx);
  const float c00 = (1.f - fy) * (1.f - fx), c01 = (1.f - fy) * fx;
  const float c10 = fy * (1.f - fx),         c11 = fy * fx;
  const int wv = t >> 6;
  const int l  = t & 63;
  const int lr = l & 15;           // row-in-tile
  const int lk = (l >> 4) << 3;    // k-offset within 32-chunk: 0,8,16,24
  uint32_t* Wtu = (uint32_t*)Wt;
  f32x4 acc[4][2][2] = {};
#pragma unroll 1
  for (int k = 0; k < 4; ++k) {
    if (k) __syncthreads();        // previous MFMA's LDS reads done before rebuild
    const uint16_t* wk = wr + ((size_t)k << 22);  // k * 256 * 16384
    const uint4* rA = (const uint4*)(wk + (((size_t)(y0 << 4) + x0) << 14));
    const uint4* rB = (const uint4*)(wk + (((size_t)(y0 << 4) + x1) << 14));
    const uint4* rC = (const uint4*)(wk + (((size_t)(y1 << 4) + x0) << 14));
    const uint4* rD = (const uint4*)(wk + (((size_t)(y1 << 4) + x1) << 14));
    // ---- build Wt[o][i] (coalesced 16B reads, interp in f32) ----
#pragma unroll
    for (int j = 0; j < 8; ++j) {
      const int fi = t + (j << 8);   // uint4 index 0..2047
      const int o  = fi >> 4;
      const int i8 = fi & 15;        // x8 elems
      const uint4 a = rA[fi], b = rB[fi], c = rC[fi], d = rD[fi];
      uint32_t ou[4];
#pragma unroll
      for (int cc = 0; cc < 4; ++cc) {
        const uint32_t ua = (&a.x)[cc], ub = (&b.x)[cc], uc = (&c.x)[cc], ud = (&d.x)[cc];
        float lo = c00 * __uint_as_float(ua << 16) + c01 * __uint_as_float(ub << 16)
                 + c10 * __uint_as_float(uc << 16) + c11 * __uint_as_float(ud << 16);
        float hi = c00 * __uint_as_float(ua & 0xffff0000u) + c01 * __uint_as_float(ub & 0xffff0000u)
                 + c10 * __uint_as_float(uc & 0xffff0000u) + c11 * __uint_as_float(ud & 0xffff0000u);
        ou[cc] = f2bf(lo) | (f2bf(hi) << 16);
      }
      *(uint4*)(Wtu + o * 68 + (i8 << 2)) = make_uint4(ou[0], ou[1], ou[2], ou[3]);
    }
    __syncthreads();
    // ---- MFMA 32(b) x 128(o) x 128(i); wave wv owns o in [32wv, 32wv+32) ----
    const uint16_t* gA = bands + (((size_t)(k << 10) + p) << 12);
    bf16x8 af[2][4], bg[2][4];
#pragma unroll
    for (int s = 0; s < 4; ++s) {
#pragma unroll
      for (int m = 0; m < 2; ++m)
        af[m][s] = *(const bf16x8*)(gA + (((m << 4) + lr) << 7) + (s << 5) + lk);
#pragma unroll
      for (int n = 0; n < 2; ++n)
        bg[n][s] = *(const bf16x8*)(&Wt[((wv << 5) + (n << 4) + lr) * 136 + (s << 5) + lk]);
    }
#pragma unroll
    for (int s = 0; s < 4; ++s)
#pragma unroll
      for (int m = 0; m < 2; ++m)
#pragma unroll
        for (int n = 0; n < 2; ++n)
          acc[k][m][n] = __builtin_amdgcn_mfma_f32_16x16x32_bf16(af[m][s], bg[n][s], acc[k][m][n], 0, 0, 0);
  }
  // ---- in-register Haar combine + zero-band upsample + direct store ----
  // acc[0]=ll-out, acc[1]=lh-out, acc[2]=hl-out, acc[3]=hh-out at (b_,o_).
#pragma unroll
  for (int m = 0; m < 2; ++m)
#pragma unroll
    for (int n = 0; n < 2; ++n)
#pragma unroll
      for (int r = 0; r < 4; ++r) {
        const int b_ = (m << 4) + ((l >> 4) << 2) + r;          // batch row
        const int o_ = (wv << 5) + (n << 4) + lr;               // out channel
        const float A = acc[0][m][n][r], B = acc[1][m][n][r];
        const float C = acc[2][m][n][r], D = acc[3][m][n][r];
        const float E = A + B, F = A - B, G = C + D, Hh = C - D;
        const float vL0 = 0.25f * (E + G),  vR0 = 0.25f * (F + Hh);  // rows 4h+0,1
        const float vL1 = 0.25f * (E - G),  vR1 = 0.25f * (F - Hh);  // rows 4h+2,3
        float* ob = out + (((size_t)(b_ << 7) + o_) << 14) + (h << 9) + (w << 2);
        float4 top = make_float4(vL0, vL0, vR0, vR0);
        float4 bot = make_float4(vL1, vL1, vR1, vR1);
        *(float4*)(ob)       = top;
        *(float4*)(ob + 128) = top;
        *(float4*)(ob + 256) = bot;
        *(float4*)(ob + 384) = bot;
      }
}

extern "C" void kernel_launch(void* const* d_in, const int* in_sizes, int n_in,
                              void* d_out, int out_size, void* d_ws, size_t ws_size,
                              hipStream_t stream) {
  const float* x  = (const float*)d_in[0];
  const float* w1 = (const float*)d_in[1];
  const float* w2 = (const float*)d_in[2];
  const float* w3 = (const float*)d_in[3];
  const float* w4 = (const float*)d_in[4];

  uint16_t* bands = (uint16_t*)d_ws;            // 4*1024*4096 bf16 = 33.5 MB
  uint16_t* wr    = bands + (size_t)16777216;   // 33.5 MB (replaces freed ws2 slot)

  wrepack_kernel<<<512, 256, 0, stream>>>(w1, w2, w3, w4, wr);
  dwt_kernel<<<4096, 256, 0, stream>>>(x, bands);
  tail_kernel<<<1024, 256, 0, stream>>>(bands, wr, (float*)d_out);
}